// Round 3
// baseline (234.733 us; speedup 1.0000x reference)
//
#include <hip/hip_runtime.h>

#define EPS 1e-5f

#define BATCH 16
#define LEN   1024
#define C0    8
#define C1    32
#define C2    64
#define NODES 128
#define NF1   100
#define NF2   128

// workspace layout (float offsets). Every word read is written earlier in the
// same iteration; cross-kernel visibility comes from dispatch boundaries.
#define OFF_C1   0          // 16*32*1024 = 524288
#define OFF_C2   524288     // 16*64*1024 = 1048576
#define OFF_S1P  1572864    // 256 blocks * 64
#define OFF_S2P  1589248    // 256 blocks * 128
#define OFF_ZZP  1622016    // 4 jt * 16 n * 100 = 6400

// ---------------- kA: conv1 (8->32, K=5, pad 2) + bias -> c1, BN1 block partials
__global__ __launch_bounds__(256)
void kA(const float* __restrict__ x, const float* __restrict__ w,
        const float* __restrict__ bias, float* __restrict__ c1,
        float* __restrict__ s1p) {
    int tid = threadIdx.x, b = blockIdx.x;
    int lane = tid & 63, wave = tid >> 6;
    int n = b >> 4, lt = b & 15;
    int l = lt * 64 + lane;
    int cg8 = __builtin_amdgcn_readfirstlane(wave * 8);

    float xr[5][8];
#pragma unroll
    for (int dl = 0; dl < 5; ++dl) {
        int lw = l + dl - 2;
        if (lw >= 0 && lw < LEN) {
            const float4* p = (const float4*)(x + ((size_t)n * LEN + lw) * C0);
            float4 a = p[0], b4 = p[1];
            xr[dl][0] = a.x;  xr[dl][1] = a.y;  xr[dl][2] = a.z;  xr[dl][3] = a.w;
            xr[dl][4] = b4.x; xr[dl][5] = b4.y; xr[dl][6] = b4.z; xr[dl][7] = b4.w;
        } else {
#pragma unroll
            for (int ci = 0; ci < 8; ++ci) xr[dl][ci] = 0.f;
        }
    }
#pragma unroll
    for (int u = 0; u < 8; ++u) {
        int c = cg8 + u;
        float acc = bias[c];
        const float* wc = w + c * 40;
#pragma unroll
        for (int ci = 0; ci < 8; ++ci)
#pragma unroll
            for (int dl = 0; dl < 5; ++dl)
                acc += xr[dl][ci] * wc[ci * 5 + dl];
        c1[((size_t)n * C1 + c) * LEN + l] = acc;

        float s = acc, q = acc * acc;
#pragma unroll
        for (int off = 32; off >= 1; off >>= 1) {
            s += __shfl_xor(s, off);
            q += __shfl_xor(q, off);
        }
        if (lane == 0) {
            s1p[b * 64 + c * 2]     = s;
            s1p[b * 64 + c * 2 + 1] = q;
        }
    }
}

// ---------------- kB: BN1 reduce; BN1+ReLU -> conv2 (32->64) -> c2, BN2 partials
__global__ __launch_bounds__(256)
void kB(const float* __restrict__ c1, const float* __restrict__ w,
        const float* __restrict__ bias,
        const float* __restrict__ g1, const float* __restrict__ bb1,
        const float* __restrict__ s1p,
        float* __restrict__ c2, float* __restrict__ s2p) {
    int tid = threadIdx.x, b = blockIdx.x;
    int lane = tid & 63, wave = tid >> 6;

    __shared__ float sc1[32], sh1[32];
    __shared__ __align__(16) float a1[32 * 68];
    __shared__ float redw[256];

    // reduce s1p: wave w sums blocks w*64..+63 for value 'lane' (coalesced, 8 accs)
    {
        float a0=0,a1_=0,a2=0,a3=0,a4=0,a5=0,a6=0,a7=0;
        int b0 = wave * 64;
        for (int i = 0; i < 64; i += 8) {
            a0  += s1p[(size_t)(b0+i  ) * 64 + lane];
            a1_ += s1p[(size_t)(b0+i+1) * 64 + lane];
            a2  += s1p[(size_t)(b0+i+2) * 64 + lane];
            a3  += s1p[(size_t)(b0+i+3) * 64 + lane];
            a4  += s1p[(size_t)(b0+i+4) * 64 + lane];
            a5  += s1p[(size_t)(b0+i+5) * 64 + lane];
            a6  += s1p[(size_t)(b0+i+6) * 64 + lane];
            a7  += s1p[(size_t)(b0+i+7) * 64 + lane];
        }
        redw[wave * 64 + lane] = ((a0+a1_)+(a2+a3)) + ((a4+a5)+(a6+a7));
    }
    __syncthreads();
    if (tid < 64)
        redw[tid] = redw[tid] + redw[64 + tid] + redw[128 + tid] + redw[192 + tid];
    __syncthreads();
    if (tid < 32) {
        float s = redw[tid * 2], q = redw[tid * 2 + 1];
        float mean = s * (1.f / 16384.f);
        float var  = q * (1.f / 16384.f) - mean * mean;
        float rs   = rsqrtf(var + EPS);
        float sc   = g1[tid] * rs;
        sc1[tid] = sc;
        sh1[tid] = bb1[tid] - mean * sc;
    }
    __syncthreads();

    int n = b >> 4, lt = b & 15;
    int lbase = lt * 64;

    for (int idx = tid; idx < 32 * 68; idx += 256) {
        int ci = idx / 68, lo = idx - ci * 68;
        int lg = lbase + lo - 2;
        float v = 0.f;
        if (lg >= 0 && lg < LEN) v = c1[((size_t)n * C1 + ci) * LEN + lg];
        a1[idx] = fmaxf(0.f, v * sc1[ci] + sh1[ci]);
    }
    __syncthreads();

    int l = lane;
    int cobase = __builtin_amdgcn_readfirstlane(wave * 16);

    float acc[16];
#pragma unroll
    for (int u = 0; u < 16; ++u) acc[u] = bias[cobase + u];

    for (int ci = 0; ci < 32; ++ci) {
        float v0 = a1[ci * 68 + l + 0];
        float v1 = a1[ci * 68 + l + 1];
        float v2 = a1[ci * 68 + l + 2];
        float v3 = a1[ci * 68 + l + 3];
        float v4 = a1[ci * 68 + l + 4];
#pragma unroll
        for (int u = 0; u < 16; ++u) {
            const float* wp = w + ((size_t)(cobase + u) * 32 + ci) * 5;
            acc[u] += v0 * wp[0] + v1 * wp[1] + v2 * wp[2] + v3 * wp[3] + v4 * wp[4];
        }
    }

    int lg = lbase + l;
#pragma unroll
    for (int u = 0; u < 16; ++u)
        c2[((size_t)n * C2 + cobase + u) * LEN + lg] = acc[u];

    for (int u = 0; u < 16; ++u) {
        float s = acc[u], q = acc[u] * acc[u];
#pragma unroll
        for (int off = 32; off >= 1; off >>= 1) {
            s += __shfl_xor(s, off);
            q += __shfl_xor(q, off);
        }
        if (lane == 0) {
            int c = cobase + u;
            s2p[b * 128 + c * 2]     = s;
            s2p[b * 128 + c * 2 + 1] = q;
        }
    }
}

// ---------------- kC: 64 blocks (n,jt). BN2 reduce; pool ALL i in-block; FC1 slice -> zzp
__global__ __launch_bounds__(256)
void kC(const float* __restrict__ bmat, const float* __restrict__ c2,
        const float* __restrict__ g2, const float* __restrict__ bb2,
        const float* __restrict__ s2p, const float* __restrict__ w1,
        float* __restrict__ zzp) {
    int tid = threadIdx.x, b = blockIdx.x;
    int n = b >> 2, jt = b & 3;
    int jbase = jt * 32;

    __shared__ __align__(16) float smem[6656];
    float* sc2  = smem;          // 64
    float* sh2  = smem + 64;     // 64
    float* bt   = smem + 128;    // 64*34 = 2176
    float* ht   = smem + 2304;   // 64*68 = 4352
    float* red2 = smem + 128;    // 256 (used before staging starts)

    // BN2 reduce: 128 values over 256 producer blocks
    {
        int v = tid & 127, half = tid >> 7;
        float a0=0,a1=0,a2=0,a3=0,a4=0,a5=0,a6=0,a7=0;
        int b0 = half * 128;
        for (int i = 0; i < 128; i += 8) {
            a0 += s2p[(size_t)(b0+i  ) * 128 + v];
            a1 += s2p[(size_t)(b0+i+1) * 128 + v];
            a2 += s2p[(size_t)(b0+i+2) * 128 + v];
            a3 += s2p[(size_t)(b0+i+3) * 128 + v];
            a4 += s2p[(size_t)(b0+i+4) * 128 + v];
            a5 += s2p[(size_t)(b0+i+5) * 128 + v];
            a6 += s2p[(size_t)(b0+i+6) * 128 + v];
            a7 += s2p[(size_t)(b0+i+7) * 128 + v];
        }
        red2[half * 128 + v] = ((a0+a1)+(a2+a3)) + ((a4+a5)+(a6+a7));
    }
    __syncthreads();
    if (tid < 128) red2[tid] += red2[128 + tid];
    __syncthreads();
    if (tid < 64) {
        float s = red2[tid * 2], q = red2[tid * 2 + 1];
        float mean = s * (1.f / 16384.f);
        float var  = q * (1.f / 16384.f) - mean * mean;
        float rs   = rsqrtf(var + EPS);
        float sc   = g2[tid] * rs;
        sc2[tid] = sc;
        sh2[tid] = bb2[tid] - mean * sc;
    }
    __syncthreads();

    float mx[2][4];
#pragma unroll
    for (int a = 0; a < 2; ++a)
#pragma unroll
        for (int c = 0; c < 4; ++c) mx[a][c] = 0.f;

    int jj = (tid >> 4) * 2, kk = (tid & 15) * 4;

    // staging addresses (fixed per thread)
    int il = tid >> 2, jq = tid & 3;        // b tile role
    int kc = tid >> 2, iq = tid & 3;        // h tile role
    float scl = sc2[kc], shl = sh2[kc];

    // register prefetch of tile 0
    float4 pb0, pb1, ph0, ph1, ph2, ph3;
    {
        const float4* p = (const float4*)(bmat + ((size_t)n * LEN + 0 + il) * NODES + jbase + jq * 8);
        pb0 = p[0]; pb1 = p[1];
        const float4* q = (const float4*)(c2 + ((size_t)n * C2 + kc) * LEN + 0 + iq * 16);
        ph0 = q[0]; ph1 = q[1]; ph2 = q[2]; ph3 = q[3];
    }

    for (int ic = 0; ic < 16; ++ic) {
        __syncthreads();   // previous inner loop done reading bt/ht
        {   // write staged tile from regs
            float* d = &bt[il * 34 + jq * 8];
            d[0] = pb0.x; d[1] = pb0.y; d[2] = pb0.z; d[3] = pb0.w;
            d[4] = pb1.x; d[5] = pb1.y; d[6] = pb1.z; d[7] = pb1.w;
            float4 hv[4] = {ph0, ph1, ph2, ph3};
#pragma unroll
            for (int r = 0; r < 4; ++r) {
                int i0 = iq * 16 + r * 4;
                ht[(i0 + 0) * 68 + kc] = fmaxf(0.f, hv[r].x * scl + shl);
                ht[(i0 + 1) * 68 + kc] = fmaxf(0.f, hv[r].y * scl + shl);
                ht[(i0 + 2) * 68 + kc] = fmaxf(0.f, hv[r].z * scl + shl);
                ht[(i0 + 3) * 68 + kc] = fmaxf(0.f, hv[r].w * scl + shl);
            }
        }
        __syncthreads();
        if (ic + 1 < 16) {  // issue next-tile loads; latency hides under inner loop
            int ib = (ic + 1) * 64;
            const float4* p = (const float4*)(bmat + ((size_t)n * LEN + ib + il) * NODES + jbase + jq * 8);
            pb0 = p[0]; pb1 = p[1];
            const float4* q = (const float4*)(c2 + ((size_t)n * C2 + kc) * LEN + ib + iq * 16);
            ph0 = q[0]; ph1 = q[1]; ph2 = q[2]; ph3 = q[3];
        }
#pragma unroll 4
        for (int i = 0; i < 64; ++i) {
            float2 bv = *(const float2*)&bt[i * 34 + jj];
            float4 hv = *(const float4*)&ht[i * 68 + kk];
            mx[0][0] = fmaxf(mx[0][0], bv.x * hv.x);
            mx[0][1] = fmaxf(mx[0][1], bv.x * hv.y);
            mx[0][2] = fmaxf(mx[0][2], bv.x * hv.z);
            mx[0][3] = fmaxf(mx[0][3], bv.x * hv.w);
            mx[1][0] = fmaxf(mx[1][0], bv.y * hv.x);
            mx[1][1] = fmaxf(mx[1][1], bv.y * hv.y);
            mx[1][2] = fmaxf(mx[1][2], bv.y * hv.z);
            mx[1][3] = fmaxf(mx[1][3], bv.y * hv.w);
        }
    }
    __syncthreads();   // done with bt/ht; reuse smem for z chunk

    // z chunk in LDS: zl[jlocal*64 + k], 2048 floats
    float* zl = smem;
    *(float4*)&zl[(jj + 0) * 64 + kk] = make_float4(mx[0][0], mx[0][1], mx[0][2], mx[0][3]);
    *(float4*)&zl[(jj + 1) * 64 + kk] = make_float4(mx[1][0], mx[1][1], mx[1][2], mx[1][3]);
    __syncthreads();

    // FC1 slice: each wave handles 25 features; 25 per-lane accumulators (unrolled -> regs)
    {
        int wv = tid >> 6, ln = tid & 63;
        float4 zr[8];
#pragma unroll
        for (int e = 0; e < 8; ++e)
            zr[e] = *(float4*)&zl[e * 256 + ln * 4];

        float s[25];
        const float* wbase = w1 + (size_t)(wv * 25) * 8192 + jbase * 64;
#pragma unroll
        for (int t = 0; t < 25; ++t) {
            const float* wp = wbase + (size_t)t * 8192;
            float acc = 0.f;
#pragma unroll
            for (int e = 0; e < 8; ++e) {
                float4 w4 = *(const float4*)&wp[e * 256 + ln * 4];
                acc += zr[e].x * w4.x + zr[e].y * w4.y + zr[e].z * w4.z + zr[e].w * w4.w;
            }
            s[t] = acc;
        }
#pragma unroll
        for (int t = 0; t < 25; ++t) {
            float v = s[t];
#pragma unroll
            for (int off = 32; off >= 1; off >>= 1) v += __shfl_xor(v, off);
            if (ln == 0) zzp[((size_t)jt * 16 + n) * 100 + wv * 25 + t] = v;
        }
    }
}

// ---------------- kD: 1 block: combine zzp + b1, BN3 over batch, ReLU, FC2 (+b2) -> out
__global__ __launch_bounds__(256)
void kD(const float* __restrict__ zzp, const float* __restrict__ b1f,
        const float* __restrict__ g3, const float* __restrict__ b3,
        const float* __restrict__ w2, const float* __restrict__ b2f,
        float* __restrict__ out) {
    int tid = threadIdx.x;
    __shared__ float zzl[BATCH * NF1];
    __shared__ float sc3[NF1], sh3[NF1];

    for (int idx = tid; idx < BATCH * NF1; idx += 256) {
        int f = idx % NF1;
        zzl[idx] = zzp[idx] + zzp[1600 + idx] + zzp[3200 + idx] + zzp[4800 + idx] + b1f[f];
    }
    __syncthreads();
    if (tid < NF1) {
        float s = 0.f, q = 0.f;
#pragma unroll
        for (int m = 0; m < BATCH; ++m) {
            float v = zzl[m * NF1 + tid];
            s += v; q += v * v;
        }
        float mean = s * (1.f / 16.f);
        float var  = q * (1.f / 16.f) - mean * mean;
        float rs   = rsqrtf(var + EPS);
        float sc   = g3[tid] * rs;
        sc3[tid] = sc;
        sh3[tid] = b3[tid] - mean * sc;
    }
    __syncthreads();
    for (int idx = tid; idx < BATCH * NF1; idx += 256) {
        int f = idx % NF1;
        zzl[idx] = fmaxf(0.f, zzl[idx] * sc3[f] + sh3[f]);
    }
    __syncthreads();

    {
        int o = tid & 127, half = tid >> 7;
        float acc[8];
#pragma unroll
        for (int nn = 0; nn < 8; ++nn) acc[nn] = b2f[o];
        const float* wr = w2 + (size_t)o * NF1;
        for (int f = 0; f < NF1; ++f) {
            float wvv = wr[f];
#pragma unroll
            for (int nn = 0; nn < 8; ++nn)
                acc[nn] += zzl[(half * 8 + nn) * NF1 + f] * wvv;
        }
#pragma unroll
        for (int nn = 0; nn < 8; ++nn)
            out[(half * 8 + nn) * NF2 + o] = acc[nn];
    }
}

extern "C" void kernel_launch(void* const* d_in, const int* in_sizes, int n_in,
                              void* d_out, int out_size, void* d_ws, size_t ws_size,
                              hipStream_t stream) {
    const float* x    = (const float*)d_in[0];
    const float* bmat = (const float*)d_in[1];
    const float* c1w  = (const float*)d_in[2];
    const float* c1b  = (const float*)d_in[3];
    const float* g1   = (const float*)d_in[4];
    const float* bb1  = (const float*)d_in[5];
    const float* c2w  = (const float*)d_in[6];
    const float* c2b  = (const float*)d_in[7];
    const float* g2   = (const float*)d_in[8];
    const float* bb2  = (const float*)d_in[9];
    const float* w1   = (const float*)d_in[10];
    const float* b1   = (const float*)d_in[11];
    const float* g3   = (const float*)d_in[12];
    const float* b3   = (const float*)d_in[13];
    const float* w2   = (const float*)d_in[14];
    const float* b2   = (const float*)d_in[15];
    float* out = (float*)d_out;
    float* ws  = (float*)d_ws;

    float* c1  = ws + OFF_C1;
    float* c2  = ws + OFF_C2;
    float* s1p = ws + OFF_S1P;
    float* s2p = ws + OFF_S2P;
    float* zzp = ws + OFF_ZZP;

    kA<<<256, 256, 0, stream>>>(x, c1w, c1b, c1, s1p);
    kB<<<256, 256, 0, stream>>>(c1, c2w, c2b, g1, bb1, s1p, c2, s2p);
    kC<<<64, 256, 0, stream>>>(bmat, c2, g2, bb2, s2p, w1, zzp);
    kD<<<1, 256, 0, stream>>>(zzp, b1, g3, b3, w2, b2, out);
}

// Round 4
// 164.598 us; speedup vs baseline: 1.4261x; 1.4261x over previous
//
#include <hip/hip_runtime.h>

#define EPS 1e-5f

#define BATCH 16
#define LEN   1024
#define C0    8
#define C1    32
#define C2    64
#define NODES 128
#define NF1   100
#define NF2   128

// workspace layout (float offsets). All zeroing done by earlier kernels in the
// same iteration (z zeroed by kB); no memset dispatch, no atomicsAdd buffers.
#define OFF_C1   0          // 16*32*1024 = 524288
#define OFF_C2   524288     // 16*64*1024 = 1048576
#define OFF_S1P  1572864    // 256 blocks * 64
#define OFF_S2P  1589248    // 256 blocks * 128
#define OFF_Z    1622016    // 16*128*64 = 131072 (zeroed by kB, atomicMax by kC)
#define OFF_ZZP  1753088    // 4 kq * 16 n * 100 = 6400

// ---------------- kA: conv1 (8->32, K=5, pad 2) + bias -> c1, BN1 block partials
__global__ __launch_bounds__(256)
void kA(const float* __restrict__ x, const float* __restrict__ w,
        const float* __restrict__ bias, float* __restrict__ c1,
        float* __restrict__ s1p) {
    int tid = threadIdx.x, b = blockIdx.x;
    int lane = tid & 63, wave = tid >> 6;
    int n = b >> 4, lt = b & 15;
    int l = lt * 64 + lane;
    int cg8 = __builtin_amdgcn_readfirstlane(wave * 8);

    float xr[5][8];
#pragma unroll
    for (int dl = 0; dl < 5; ++dl) {
        int lw = l + dl - 2;
        if (lw >= 0 && lw < LEN) {
            const float4* p = (const float4*)(x + ((size_t)n * LEN + lw) * C0);
            float4 a = p[0], b4 = p[1];
            xr[dl][0] = a.x;  xr[dl][1] = a.y;  xr[dl][2] = a.z;  xr[dl][3] = a.w;
            xr[dl][4] = b4.x; xr[dl][5] = b4.y; xr[dl][6] = b4.z; xr[dl][7] = b4.w;
        } else {
#pragma unroll
            for (int ci = 0; ci < 8; ++ci) xr[dl][ci] = 0.f;
        }
    }
#pragma unroll
    for (int u = 0; u < 8; ++u) {
        int c = cg8 + u;
        float acc = bias[c];
        const float* wc = w + c * 40;
#pragma unroll
        for (int ci = 0; ci < 8; ++ci)
#pragma unroll
            for (int dl = 0; dl < 5; ++dl)
                acc += xr[dl][ci] * wc[ci * 5 + dl];
        c1[((size_t)n * C1 + c) * LEN + l] = acc;

        float s = acc, q = acc * acc;
#pragma unroll
        for (int off = 32; off >= 1; off >>= 1) {
            s += __shfl_xor(s, off);
            q += __shfl_xor(q, off);
        }
        if (lane == 0) {
            s1p[b * 64 + c * 2]     = s;
            s1p[b * 64 + c * 2 + 1] = q;
        }
    }
}

// ---------------- kB: BN1 reduce; BN1+ReLU -> conv2 (32->64) -> c2, BN2 partials; zero z
__global__ __launch_bounds__(256)
void kB(const float* __restrict__ c1, const float* __restrict__ w,
        const float* __restrict__ bias,
        const float* __restrict__ g1, const float* __restrict__ bb1,
        const float* __restrict__ s1p,
        float* __restrict__ c2, float* __restrict__ s2p,
        float* __restrict__ z) {
    int tid = threadIdx.x, b = blockIdx.x;
    int lane = tid & 63, wave = tid >> 6;

    // zero this block's 512-float slice of z (for kC's atomicMax)
    if (tid < 128)
        ((float4*)(z + (size_t)b * 512))[tid] = make_float4(0.f, 0.f, 0.f, 0.f);

    __shared__ float sc1[32], sh1[32];
    __shared__ __align__(16) float a1[32 * 68];
    __shared__ float redw[256];

    // reduce s1p: wave w sums blocks w*64..+63 for value 'lane' (coalesced, 8 accs)
    {
        float a0=0,a1_=0,a2=0,a3=0,a4=0,a5=0,a6=0,a7=0;
        int b0 = wave * 64;
        for (int i = 0; i < 64; i += 8) {
            a0  += s1p[(size_t)(b0+i  ) * 64 + lane];
            a1_ += s1p[(size_t)(b0+i+1) * 64 + lane];
            a2  += s1p[(size_t)(b0+i+2) * 64 + lane];
            a3  += s1p[(size_t)(b0+i+3) * 64 + lane];
            a4  += s1p[(size_t)(b0+i+4) * 64 + lane];
            a5  += s1p[(size_t)(b0+i+5) * 64 + lane];
            a6  += s1p[(size_t)(b0+i+6) * 64 + lane];
            a7  += s1p[(size_t)(b0+i+7) * 64 + lane];
        }
        redw[wave * 64 + lane] = ((a0+a1_)+(a2+a3)) + ((a4+a5)+(a6+a7));
    }
    __syncthreads();
    if (tid < 64)
        redw[tid] = redw[tid] + redw[64 + tid] + redw[128 + tid] + redw[192 + tid];
    __syncthreads();
    if (tid < 32) {
        float s = redw[tid * 2], q = redw[tid * 2 + 1];
        float mean = s * (1.f / 16384.f);
        float var  = q * (1.f / 16384.f) - mean * mean;
        float rs   = rsqrtf(var + EPS);
        float sc   = g1[tid] * rs;
        sc1[tid] = sc;
        sh1[tid] = bb1[tid] - mean * sc;
    }
    __syncthreads();

    int n = b >> 4, lt = b & 15;
    int lbase = lt * 64;

    for (int idx = tid; idx < 32 * 68; idx += 256) {
        int ci = idx / 68, lo = idx - ci * 68;
        int lg = lbase + lo - 2;
        float v = 0.f;
        if (lg >= 0 && lg < LEN) v = c1[((size_t)n * C1 + ci) * LEN + lg];
        a1[idx] = fmaxf(0.f, v * sc1[ci] + sh1[ci]);
    }
    __syncthreads();

    int l = lane;
    int cobase = __builtin_amdgcn_readfirstlane(wave * 16);

    float acc[16];
#pragma unroll
    for (int u = 0; u < 16; ++u) acc[u] = bias[cobase + u];

    for (int ci = 0; ci < 32; ++ci) {
        float v0 = a1[ci * 68 + l + 0];
        float v1 = a1[ci * 68 + l + 1];
        float v2 = a1[ci * 68 + l + 2];
        float v3 = a1[ci * 68 + l + 3];
        float v4 = a1[ci * 68 + l + 4];
#pragma unroll
        for (int u = 0; u < 16; ++u) {
            const float* wp = w + ((size_t)(cobase + u) * 32 + ci) * 5;
            acc[u] += v0 * wp[0] + v1 * wp[1] + v2 * wp[2] + v3 * wp[3] + v4 * wp[4];
        }
    }

    int lg = lbase + l;
#pragma unroll
    for (int u = 0; u < 16; ++u)
        c2[((size_t)n * C2 + cobase + u) * LEN + lg] = acc[u];

    for (int u = 0; u < 16; ++u) {
        float s = acc[u], q = acc[u] * acc[u];
#pragma unroll
        for (int off = 32; off >= 1; off >>= 1) {
            s += __shfl_xor(s, off);
            q += __shfl_xor(q, off);
        }
        if (lane == 0) {
            int c = cobase + u;
            s2p[b * 128 + c * 2]     = s;
            s2p[b * 128 + c * 2 + 1] = q;
        }
    }
}

// ---------------- kC: 256 blocks (jt,is,n). BN2 reduce; BN2+ReLU + pool partial; atomicMax z
__global__ __launch_bounds__(256)
void kC(const float* __restrict__ bmat, const float* __restrict__ c2,
        const float* __restrict__ g2, const float* __restrict__ bb2,
        const float* __restrict__ s2p, float* __restrict__ z) {
    int tid = threadIdx.x;
    int jt = blockIdx.x, is = blockIdx.y, n = blockIdx.z;
    int jbase = jt * 32;
    int ibase0 = is * 256;

    __shared__ float sc2[64], sh2[64];
    __shared__ __align__(16) float bt[64 * 34];
    __shared__ __align__(16) float ht[64 * 68];
    __shared__ float red2[256];

    // BN2 reduce: 128 (s,q) values over 256 producer blocks
    {
        int v = tid & 127, half = tid >> 7;
        float a0=0,a1=0,a2=0,a3=0,a4=0,a5=0,a6=0,a7=0;
        int b0 = half * 128;
        for (int i = 0; i < 128; i += 8) {
            a0 += s2p[(size_t)(b0+i  ) * 128 + v];
            a1 += s2p[(size_t)(b0+i+1) * 128 + v];
            a2 += s2p[(size_t)(b0+i+2) * 128 + v];
            a3 += s2p[(size_t)(b0+i+3) * 128 + v];
            a4 += s2p[(size_t)(b0+i+4) * 128 + v];
            a5 += s2p[(size_t)(b0+i+5) * 128 + v];
            a6 += s2p[(size_t)(b0+i+6) * 128 + v];
            a7 += s2p[(size_t)(b0+i+7) * 128 + v];
        }
        red2[half * 128 + v] = ((a0+a1)+(a2+a3)) + ((a4+a5)+(a6+a7));
    }
    __syncthreads();
    if (tid < 128) red2[tid] += red2[128 + tid];
    __syncthreads();
    if (tid < 64) {
        float s = red2[tid * 2], q = red2[tid * 2 + 1];
        float mean = s * (1.f / 16384.f);
        float var  = q * (1.f / 16384.f) - mean * mean;
        float rs   = rsqrtf(var + EPS);
        float sc   = g2[tid] * rs;
        sc2[tid] = sc;
        sh2[tid] = bb2[tid] - mean * sc;
    }
    __syncthreads();

    float mx[2][4];
#pragma unroll
    for (int a = 0; a < 2; ++a)
#pragma unroll
        for (int c = 0; c < 4; ++c) mx[a][c] = 0.f;

    int jj = (tid >> 4) * 2, kk = (tid & 15) * 4;

    for (int ic = 0; ic < 4; ++ic) {
        int ib = ibase0 + ic * 64;
        {   // stage b tile [64 i][32 j], pad stride 34
            int il = tid >> 2, jq = tid & 3;
            const float4* p = (const float4*)(bmat + ((size_t)n * LEN + ib + il) * NODES + jbase + jq * 8);
            float4 a = p[0], b4 = p[1];
            float* d = &bt[il * 34 + jq * 8];
            d[0] = a.x;  d[1] = a.y;  d[2] = a.z;  d[3] = a.w;
            d[4] = b4.x; d[5] = b4.y; d[6] = b4.z; d[7] = b4.w;
        }
        {   // stage h tile [64 i][64 k] transposed, BN2+ReLU, pad stride 68
            int kc = tid >> 2, iq = tid & 3;
            float sc = sc2[kc], sh = sh2[kc];
            const float4* p = (const float4*)(c2 + ((size_t)n * C2 + kc) * LEN + ib + iq * 16);
#pragma unroll
            for (int r = 0; r < 4; ++r) {
                float4 hv = p[r];
                int i0 = iq * 16 + r * 4;
                ht[(i0 + 0) * 68 + kc] = fmaxf(0.f, hv.x * sc + sh);
                ht[(i0 + 1) * 68 + kc] = fmaxf(0.f, hv.y * sc + sh);
                ht[(i0 + 2) * 68 + kc] = fmaxf(0.f, hv.z * sc + sh);
                ht[(i0 + 3) * 68 + kc] = fmaxf(0.f, hv.w * sc + sh);
            }
        }
        __syncthreads();
#pragma unroll 4
        for (int i = 0; i < 64; ++i) {
            float2 bv = *(const float2*)&bt[i * 34 + jj];
            float4 hv = *(const float4*)&ht[i * 68 + kk];
            mx[0][0] = fmaxf(mx[0][0], bv.x * hv.x);
            mx[0][1] = fmaxf(mx[0][1], bv.x * hv.y);
            mx[0][2] = fmaxf(mx[0][2], bv.x * hv.z);
            mx[0][3] = fmaxf(mx[0][3], bv.x * hv.w);
            mx[1][0] = fmaxf(mx[1][0], bv.y * hv.x);
            mx[1][1] = fmaxf(mx[1][1], bv.y * hv.y);
            mx[1][2] = fmaxf(mx[1][2], bv.y * hv.z);
            mx[1][3] = fmaxf(mx[1][3], bv.y * hv.w);
        }
        __syncthreads();
    }
#pragma unroll
    for (int a = 0; a < 2; ++a)
#pragma unroll
        for (int c = 0; c < 4; ++c) {
            int j = jbase + jj + a, k = kk + c;
            atomicMax((unsigned int*)&z[((size_t)n * NODES + j) * 64 + k],
                      __float_as_uint(mx[a][c]));
        }
}

// ---------------- kD: FC1 partial dots (deterministic): zzp[kq][n][f]
__global__ __launch_bounds__(256)
void kD(const float* __restrict__ zbuf, const float* __restrict__ w1,
        float* __restrict__ zzp) {
    int tid = threadIdx.x;
    int f = blockIdx.x, kq = blockIdx.y;
    int base = kq * 2048;

    float acc[16];
#pragma unroll
    for (int n = 0; n < 16; ++n) acc[n] = 0.f;

    for (int q = 0; q < 8; ++q) {
        int idx = base + q * 256 + tid;
        float wv = w1[(size_t)f * 8192 + idx];
#pragma unroll
        for (int n = 0; n < 16; ++n)
            acc[n] += wv * zbuf[(size_t)n * 8192 + idx];
    }

    __shared__ float red[4][16];
    int lane = tid & 63, wave = tid >> 6;
    for (int n = 0; n < 16; ++n) {
        float s = acc[n];
#pragma unroll
        for (int off = 32; off >= 1; off >>= 1) s += __shfl_xor(s, off);
        if (lane == 0) red[wave][n] = s;
    }
    __syncthreads();
    if (tid < 16)
        zzp[(size_t)kq * 1600 + tid * NF1 + f]
            = red[0][tid] + red[1][tid] + red[2][tid] + red[3][tid];
}

// ---------------- kE: combine zzp + b1, BN3 over batch, ReLU, FC2 (+b2) -> out
__global__ __launch_bounds__(128)
void kE(const float* __restrict__ zzp, const float* __restrict__ b1f,
        const float* __restrict__ g3, const float* __restrict__ b3,
        const float* __restrict__ w2, const float* __restrict__ b2f,
        float* __restrict__ out) {
    int tid = threadIdx.x;
    int n = blockIdx.x;

    __shared__ float zzl[BATCH * NF1];
    __shared__ float sc3[NF1], sh3[NF1];

    for (int idx = tid; idx < BATCH * NF1; idx += 128) {
        int f = idx % NF1;
        zzl[idx] = zzp[idx] + zzp[1600 + idx] + zzp[3200 + idx] + zzp[4800 + idx] + b1f[f];
    }
    __syncthreads();
    if (tid < NF1) {
        float s = 0.f, q = 0.f;
#pragma unroll
        for (int m = 0; m < BATCH; ++m) {
            float v = zzl[m * NF1 + tid];
            s += v; q += v * v;
        }
        float mean = s * (1.f / 16.f);
        float var  = q * (1.f / 16.f) - mean * mean;
        float rs   = rsqrtf(var + EPS);
        float sc   = g3[tid] * rs;
        sc3[tid] = sc;
        sh3[tid] = b3[tid] - mean * sc;
    }
    __syncthreads();
    for (int idx = tid; idx < BATCH * NF1; idx += 128) {
        int f = idx % NF1;
        zzl[idx] = fmaxf(0.f, zzl[idx] * sc3[f] + sh3[f]);
    }
    __syncthreads();

    float acc = b2f[tid];
    const float* wr = w2 + (size_t)tid * NF1;
    const float* zr = &zzl[n * NF1];
#pragma unroll 4
    for (int f = 0; f < NF1; ++f)
        acc += zr[f] * wr[f];
    out[n * NF2 + tid] = acc;
}

extern "C" void kernel_launch(void* const* d_in, const int* in_sizes, int n_in,
                              void* d_out, int out_size, void* d_ws, size_t ws_size,
                              hipStream_t stream) {
    const float* x    = (const float*)d_in[0];
    const float* bmat = (const float*)d_in[1];
    const float* c1w  = (const float*)d_in[2];
    const float* c1b  = (const float*)d_in[3];
    const float* g1   = (const float*)d_in[4];
    const float* bb1  = (const float*)d_in[5];
    const float* c2w  = (const float*)d_in[6];
    const float* c2b  = (const float*)d_in[7];
    const float* g2   = (const float*)d_in[8];
    const float* bb2  = (const float*)d_in[9];
    const float* w1   = (const float*)d_in[10];
    const float* b1   = (const float*)d_in[11];
    const float* g3   = (const float*)d_in[12];
    const float* b3   = (const float*)d_in[13];
    const float* w2   = (const float*)d_in[14];
    const float* b2   = (const float*)d_in[15];
    float* out = (float*)d_out;
    float* ws  = (float*)d_ws;

    float* c1  = ws + OFF_C1;
    float* c2  = ws + OFF_C2;
    float* s1p = ws + OFF_S1P;
    float* s2p = ws + OFF_S2P;
    float* z   = ws + OFF_Z;
    float* zzp = ws + OFF_ZZP;

    kA<<<256, 256, 0, stream>>>(x, c1w, c1b, c1, s1p);
    kB<<<256, 256, 0, stream>>>(c1, c2w, c2b, g1, bb1, s1p, c2, s2p, z);
    kC<<<dim3(4, 4, 16), 256, 0, stream>>>(bmat, c2, g2, bb2, s2p, z);
    kD<<<dim3(NF1, 4), 256, 0, stream>>>(z, w1, zzp);
    kE<<<16, 128, 0, stream>>>(zzp, b1, g3, b3, w2, b2, out);
}

// Round 6
// 163.015 us; speedup vs baseline: 1.4399x; 1.0097x over previous
//
#include <hip/hip_runtime.h>

#define EPS 1e-5f

#define BATCH 16
#define LEN   1024
#define C0    8
#define C1    32
#define C2    64
#define NODES 128
#define NF1   100
#define NF2   128

// workspace layout (float offsets). Cross-kernel bulk data (c1,c2,s1p,s2p) is
// plain-stored and made visible by dispatch boundaries (proven). In-kernel
// handoff (zzp) uses atomicExch (coherent point) + ticket; cnt zeroed by kB.
#define OFF_C1   0          // 16*32*1024 = 524288
#define OFF_C2   524288     // 16*64*1024 = 1048576
#define OFF_S1P  1572864    // 256 blocks * 64
#define OFF_S2P  1589248    // 256 blocks * 128
#define OFF_ZZP  1622016    // 16 slices * 16 n * 100 f = 25600
#define OFF_CNT  1647616    // 1 uint

// ---------------- kA: conv1 (8->32, K=5, pad 2) + bias -> c1, BN1 block partials
__global__ __launch_bounds__(256)
void kA(const float* __restrict__ x, const float* __restrict__ w,
        const float* __restrict__ bias, float* __restrict__ c1,
        float* __restrict__ s1p) {
    int tid = threadIdx.x, b = blockIdx.x;
    int lane = tid & 63, wave = tid >> 6;
    int n = b >> 4, lt = b & 15;
    int l = lt * 64 + lane;
    int cg8 = __builtin_amdgcn_readfirstlane(wave * 8);

    float xr[5][8];
#pragma unroll
    for (int dl = 0; dl < 5; ++dl) {
        int lw = l + dl - 2;
        if (lw >= 0 && lw < LEN) {
            const float4* p = (const float4*)(x + ((size_t)n * LEN + lw) * C0);
            float4 a = p[0], b4 = p[1];
            xr[dl][0] = a.x;  xr[dl][1] = a.y;  xr[dl][2] = a.z;  xr[dl][3] = a.w;
            xr[dl][4] = b4.x; xr[dl][5] = b4.y; xr[dl][6] = b4.z; xr[dl][7] = b4.w;
        } else {
#pragma unroll
            for (int ci = 0; ci < 8; ++ci) xr[dl][ci] = 0.f;
        }
    }
#pragma unroll
    for (int u = 0; u < 8; ++u) {
        int c = cg8 + u;
        float acc = bias[c];
        const float* wc = w + c * 40;
#pragma unroll
        for (int ci = 0; ci < 8; ++ci)
#pragma unroll
            for (int dl = 0; dl < 5; ++dl)
                acc += xr[dl][ci] * wc[ci * 5 + dl];
        c1[((size_t)n * C1 + c) * LEN + l] = acc;

        float s = acc, q = acc * acc;
#pragma unroll
        for (int off = 32; off >= 1; off >>= 1) {
            s += __shfl_xor(s, off);
            q += __shfl_xor(q, off);
        }
        if (lane == 0) {
            s1p[b * 64 + c * 2]     = s;
            s1p[b * 64 + c * 2 + 1] = q;
        }
    }
}

// ---------------- kB: BN1 reduce; BN1+ReLU -> conv2 (32->64) -> c2, BN2 partials; zero cnt
__global__ __launch_bounds__(256)
void kB(const float* __restrict__ c1, const float* __restrict__ w,
        const float* __restrict__ bias,
        const float* __restrict__ g1, const float* __restrict__ bb1,
        const float* __restrict__ s1p,
        float* __restrict__ c2, float* __restrict__ s2p,
        unsigned* __restrict__ cnt) {
    int tid = threadIdx.x, b = blockIdx.x;
    int lane = tid & 63, wave = tid >> 6;

    if (b == 0 && tid == 0) cnt[0] = 0u;   // visible to kC via dispatch boundary

    __shared__ float sc1[32], sh1[32];
    __shared__ __align__(16) float a1[32 * 68];
    __shared__ float redw[256];

    {
        float a0=0,a1_=0,a2=0,a3=0,a4=0,a5=0,a6=0,a7=0;
        int b0 = wave * 64;
        for (int i = 0; i < 64; i += 8) {
            a0  += s1p[(size_t)(b0+i  ) * 64 + lane];
            a1_ += s1p[(size_t)(b0+i+1) * 64 + lane];
            a2  += s1p[(size_t)(b0+i+2) * 64 + lane];
            a3  += s1p[(size_t)(b0+i+3) * 64 + lane];
            a4  += s1p[(size_t)(b0+i+4) * 64 + lane];
            a5  += s1p[(size_t)(b0+i+5) * 64 + lane];
            a6  += s1p[(size_t)(b0+i+6) * 64 + lane];
            a7  += s1p[(size_t)(b0+i+7) * 64 + lane];
        }
        redw[wave * 64 + lane] = ((a0+a1_)+(a2+a3)) + ((a4+a5)+(a6+a7));
    }
    __syncthreads();
    if (tid < 64)
        redw[tid] = redw[tid] + redw[64 + tid] + redw[128 + tid] + redw[192 + tid];
    __syncthreads();
    if (tid < 32) {
        float s = redw[tid * 2], q = redw[tid * 2 + 1];
        float mean = s * (1.f / 16384.f);
        float var  = q * (1.f / 16384.f) - mean * mean;
        float rs   = rsqrtf(var + EPS);
        float sc   = g1[tid] * rs;
        sc1[tid] = sc;
        sh1[tid] = bb1[tid] - mean * sc;
    }
    __syncthreads();

    int n = b >> 4, lt = b & 15;
    int lbase = lt * 64;

    for (int idx = tid; idx < 32 * 68; idx += 256) {
        int ci = idx / 68, lo = idx - ci * 68;
        int lg = lbase + lo - 2;
        float v = 0.f;
        if (lg >= 0 && lg < LEN) v = c1[((size_t)n * C1 + ci) * LEN + lg];
        a1[idx] = fmaxf(0.f, v * sc1[ci] + sh1[ci]);
    }
    __syncthreads();

    int l = lane;
    int cobase = __builtin_amdgcn_readfirstlane(wave * 16);

    float acc[16];
#pragma unroll
    for (int u = 0; u < 16; ++u) acc[u] = bias[cobase + u];

    for (int ci = 0; ci < 32; ++ci) {
        float v0 = a1[ci * 68 + l + 0];
        float v1 = a1[ci * 68 + l + 1];
        float v2 = a1[ci * 68 + l + 2];
        float v3 = a1[ci * 68 + l + 3];
        float v4 = a1[ci * 68 + l + 4];
#pragma unroll
        for (int u = 0; u < 16; ++u) {
            const float* wp = w + ((size_t)(cobase + u) * 32 + ci) * 5;
            acc[u] += v0 * wp[0] + v1 * wp[1] + v2 * wp[2] + v3 * wp[3] + v4 * wp[4];
        }
    }

    int lg = lbase + l;
#pragma unroll
    for (int u = 0; u < 16; ++u)
        c2[((size_t)n * C2 + cobase + u) * LEN + lg] = acc[u];

    for (int u = 0; u < 16; ++u) {
        float s = acc[u], q = acc[u] * acc[u];
#pragma unroll
        for (int off = 32; off >= 1; off >>= 1) {
            s += __shfl_xor(s, off);
            q += __shfl_xor(q, off);
        }
        if (lane == 0) {
            int c = cobase + u;
            s2p[b * 128 + c * 2]     = s;
            s2p[b * 128 + c * 2 + 1] = q;
        }
    }
}

// ---------------- kC: 256 blocks (n,jt,ks). BN2 reduce; pool ALL i for a 32j x 16k slice;
// FC1 partial for all 100 f -> zzp (atomicExch); ticket: 256th arriver does BN3+FC2.
__global__ __launch_bounds__(256)
void kC(const float* __restrict__ bmat, const float* __restrict__ c2,
        const float* __restrict__ g2, const float* __restrict__ bb2,
        const float* __restrict__ s2p, const float* __restrict__ w1,
        const float* __restrict__ b1f, const float* __restrict__ g3,
        const float* __restrict__ b3, const float* __restrict__ w2,
        const float* __restrict__ b2f,
        float* __restrict__ zzp, unsigned* __restrict__ cnt,
        float* __restrict__ out) {
    int tid = threadIdx.x, b = blockIdx.x;
    int lane = tid & 63, wave = tid >> 6;
    int n = b >> 4, jt = (b >> 2) & 3, ks = b & 3;
    int jbase = jt * 32, kbase = ks * 16;

    __shared__ __align__(16) float smem[4224];
    __shared__ unsigned sflag;
    float* red2 = smem;          // 256
    float* sc2s = smem + 256;    // 64
    float* sh2s = smem + 320;    // 64
    float* bt   = smem + 384;    // 64*33 = 2112 -> 2496
    float* ht   = smem + 2496;   // 64*18 = 1152 -> 3648
    float* zsl  = smem + 3648;   // 512 -> 4160
    // finisher reuse: zzl = smem[0..1600), sc3 = +1600, sh3 = +1700

    // BN2 reduce: 128 (s,q) values over 256 producer blocks
    {
        int v = tid & 127, half = tid >> 7;
        float a0=0,a1=0,a2=0,a3=0,a4=0,a5=0,a6=0,a7=0;
        int b0 = half * 128;
        for (int i = 0; i < 128; i += 8) {
            a0 += s2p[(size_t)(b0+i  ) * 128 + v];
            a1 += s2p[(size_t)(b0+i+1) * 128 + v];
            a2 += s2p[(size_t)(b0+i+2) * 128 + v];
            a3 += s2p[(size_t)(b0+i+3) * 128 + v];
            a4 += s2p[(size_t)(b0+i+4) * 128 + v];
            a5 += s2p[(size_t)(b0+i+5) * 128 + v];
            a6 += s2p[(size_t)(b0+i+6) * 128 + v];
            a7 += s2p[(size_t)(b0+i+7) * 128 + v];
        }
        red2[half * 128 + v] = ((a0+a1)+(a2+a3)) + ((a4+a5)+(a6+a7));
    }
    __syncthreads();
    if (tid < 128) red2[tid] += red2[128 + tid];
    __syncthreads();
    if (tid < 64) {
        float s = red2[tid * 2], q = red2[tid * 2 + 1];
        float mean = s * (1.f / 16384.f);
        float var  = q * (1.f / 16384.f) - mean * mean;
        float rs   = rsqrtf(var + EPS);
        float sc   = g2[tid] * rs;
        sc2s[tid] = sc;
        sh2s[tid] = bb2[tid] - mean * sc;
    }
    __syncthreads();

    // pooling: stream 16 i-tiles of 64; slice = [32 j][16 k]; 2 outputs/thread
    int jl = tid >> 3, kl2 = (tid & 7) * 2;
    float mx0 = 0.f, mx1 = 0.f;

    int il = tid >> 2, jq = tid & 3;         // bmat staging role
    int cc = tid >> 4, iq = tid & 15;        // c2 staging role
    float scl = sc2s[kbase + cc], shl = sh2s[kbase + cc];

    float4 pb0, pb1, pc0, pc1 = {};
    {
        const float4* p = (const float4*)(bmat + ((size_t)n * LEN + il) * NODES + jbase + jq * 8);
        pb0 = p[0]; pb1 = p[1];
        pc0 = *(const float4*)(c2 + ((size_t)n * C2 + kbase + cc) * LEN + iq * 4);
    }

    for (int it = 0; it < 16; ++it) {
        __syncthreads();
        {   // write staged tile from regs
            float* d = &bt[il * 33 + jq * 8];
            d[0] = pb0.x; d[1] = pb0.y; d[2] = pb0.z; d[3] = pb0.w;
            d[4] = pb1.x; d[5] = pb1.y; d[6] = pb1.z; d[7] = pb1.w;
            int i0 = iq * 4;
            ht[(i0 + 0) * 18 + cc] = fmaxf(0.f, pc0.x * scl + shl);
            ht[(i0 + 1) * 18 + cc] = fmaxf(0.f, pc0.y * scl + shl);
            ht[(i0 + 2) * 18 + cc] = fmaxf(0.f, pc0.z * scl + shl);
            ht[(i0 + 3) * 18 + cc] = fmaxf(0.f, pc0.w * scl + shl);
        }
        __syncthreads();
        if (it + 1 < 16) {   // prefetch next tile; latency hides under inner loop
            int ib = (it + 1) * 64;
            const float4* p = (const float4*)(bmat + ((size_t)n * LEN + ib + il) * NODES + jbase + jq * 8);
            pb0 = p[0]; pb1 = p[1];
            pc0 = *(const float4*)(c2 + ((size_t)n * C2 + kbase + cc) * LEN + ib + iq * 4);
        }
#pragma unroll 8
        for (int i = 0; i < 64; ++i) {
            float bv = bt[i * 33 + jl];
            float2 hv = *(const float2*)&ht[i * 18 + kl2];
            mx0 = fmaxf(mx0, bv * hv.x);
            mx1 = fmaxf(mx1, bv * hv.y);
        }
    }
    __syncthreads();
    zsl[jl * 16 + kl2]     = mx0;
    zsl[jl * 16 + kl2 + 1] = mx1;
    __syncthreads();

    // FC1 partial: zzp[slice][n][f] = sum over this 512-elem slice of z * w1
    {
        int slice = jt * 4 + ks;
        float4 z0 = *(const float4*)&zsl[lane * 8];
        float4 z1 = *(const float4*)&zsl[lane * 8 + 4];
        // flat = lane*8 -> j = lane>>1, k = (lane&1)*8
        const float* wb = w1 + (size_t)(wave * 25) * 8192
                        + (size_t)(jbase + (lane >> 1)) * 64 + kbase + (lane & 1) * 8;
        float s[25];
#pragma unroll
        for (int t = 0; t < 25; ++t) {
            const float* wp = wb + (size_t)t * 8192;
            float4 w0 = *(const float4*)wp;
            float4 w1v = *(const float4*)(wp + 4);
            s[t] = z0.x*w0.x + z0.y*w0.y + z0.z*w0.z + z0.w*w0.w
                 + z1.x*w1v.x + z1.y*w1v.y + z1.z*w1v.z + z1.w*w1v.w;
        }
#pragma unroll
        for (int t = 0; t < 25; ++t) {
            float v = s[t];
#pragma unroll
            for (int off = 32; off >= 1; off >>= 1) v += __shfl_xor(v, off);
            if (lane == 0)
                atomicExch(&zzp[(size_t)slice * 1600 + n * 100 + wave * 25 + t], v);
        }
    }

    // ---- ticket: drain own exchanges, 256th arriver proceeds (no waiting)
    asm volatile("s_waitcnt vmcnt(0)" ::: "memory");
    __syncthreads();
    if (tid == 0) {
        unsigned prev = atomicAdd(cnt, 1u);
        sflag = (prev == 255u) ? 1u : 0u;
    }
    __syncthreads();
    if (!sflag) return;

    // ---- finisher: combine 16 zzp slices + b1, BN3 over batch, ReLU, FC2 -> out
    float* zzl = smem;          // 1600
    float* sc3 = smem + 1600;   // 100
    float* sh3 = smem + 1700;   // 100

    for (int i4 = tid; i4 < 400; i4 += 256) {
        float4 a = make_float4(0.f, 0.f, 0.f, 0.f);
#pragma unroll
        for (int sI = 0; sI < 16; ++sI) {
            float4 v = *(const float4*)&zzp[(size_t)sI * 1600 + i4 * 4];
            a.x += v.x; a.y += v.y; a.z += v.z; a.w += v.w;
        }
        int flat = i4 * 4;
        zzl[flat + 0] = a.x + b1f[(flat + 0) % 100];
        zzl[flat + 1] = a.y + b1f[(flat + 1) % 100];
        zzl[flat + 2] = a.z + b1f[(flat + 2) % 100];
        zzl[flat + 3] = a.w + b1f[(flat + 3) % 100];
    }
    __syncthreads();
    if (tid < NF1) {
        float s = 0.f, q = 0.f;
#pragma unroll
        for (int m = 0; m < BATCH; ++m) {
            float v = zzl[m * NF1 + tid];
            s += v; q += v * v;
        }
        float mean = s * (1.f / 16.f);
        float var  = q * (1.f / 16.f) - mean * mean;
        float rs   = rsqrtf(var + EPS);
        float sc   = g3[tid] * rs;
        sc3[tid] = sc;
        sh3[tid] = b3[tid] - mean * sc;
    }
    __syncthreads();
    for (int t = tid; t < BATCH * NF1; t += 256) {
        int f = t % NF1;
        zzl[t] = fmaxf(0.f, zzl[t] * sc3[f] + sh3[f]);
    }
    __syncthreads();
    {
        int o = tid & 127, half = tid >> 7;
        float acc[8];
#pragma unroll
        for (int nn = 0; nn < 8; ++nn) acc[nn] = b2f[o];
        const float* wr = w2 + (size_t)o * NF1;
        for (int f = 0; f < NF1; ++f) {
            float wvv = wr[f];
#pragma unroll
            for (int nn = 0; nn < 8; ++nn)
                acc[nn] += zzl[(half * 8 + nn) * NF1 + f] * wvv;
        }
#pragma unroll
        for (int nn = 0; nn < 8; ++nn)
            out[(half * 8 + nn) * NF2 + o] = acc[nn];
    }
}

extern "C" void kernel_launch(void* const* d_in, const int* in_sizes, int n_in,
                              void* d_out, int out_size, void* d_ws, size_t ws_size,
                              hipStream_t stream) {
    const float* x    = (const float*)d_in[0];
    const float* bmat = (const float*)d_in[1];
    const float* c1w  = (const float*)d_in[2];
    const float* c1b  = (const float*)d_in[3];
    const float* g1   = (const float*)d_in[4];
    const float* bb1  = (const float*)d_in[5];
    const float* c2w  = (const float*)d_in[6];
    const float* c2b  = (const float*)d_in[7];
    const float* g2   = (const float*)d_in[8];
    const float* bb2  = (const float*)d_in[9];
    const float* w1   = (const float*)d_in[10];
    const float* b1   = (const float*)d_in[11];
    const float* g3   = (const float*)d_in[12];
    const float* b3   = (const float*)d_in[13];
    const float* w2   = (const float*)d_in[14];
    const float* b2   = (const float*)d_in[15];
    float* out = (float*)d_out;
    float* ws  = (float*)d_ws;

    float*    c1  = ws + OFF_C1;
    float*    c2  = ws + OFF_C2;
    float*    s1p = ws + OFF_S1P;
    float*    s2p = ws + OFF_S2P;
    float*    zzp = ws + OFF_ZZP;
    unsigned* cnt = (unsigned*)(ws + OFF_CNT);

    kA<<<256, 256, 0, stream>>>(x, c1w, c1b, c1, s1p);
    kB<<<256, 256, 0, stream>>>(c1, c2w, c2b, g1, bb1, s1p, c2, s2p, cnt);
    kC<<<256, 256, 0, stream>>>(bmat, c2, g2, bb2, s2p, w1, b1, g3, b3, w2, b2,
                                zzp, cnt, out);
}